// Round 4
// baseline (29.776 us; speedup 1.0000x reference)
//
#include <hip/hip_runtime.h>
#include <hip/hip_fp16.h>

#define TILE 16
#define PPT 64

#if __has_builtin(__builtin_amdgcn_exp2f)
#define EXP2F(x) __builtin_amdgcn_exp2f(x)
#else
#define EXP2F(x) exp2f(x)
#endif

__device__ __forceinline__ int read_dim(const int* p) {
    int v = *p;
    if (v >= TILE && v <= 65536 && (v % TILE) == 0) return v;
    float f = __int_as_float(v);
    return (int)f;
}

// ---------------------------------------------------------------------------
// Kernel 1: gather + preprocess each tile's points into contiguous 64B
// records (one scalar-cache line per point):
//   [0..3]  u, v, -0.5*log2e*a, -0.5*log2e*c
//   [4..7]  -log2e*b, log2(alpha), color_r, color_g
//   [8..11] color_b, depth, pad, pad
// ---------------------------------------------------------------------------
__global__ __launch_bounds__(256) void gsplat_gather_kernel(
    const float* __restrict__ point_uv,
    const float* __restrict__ point_conic,
    const float* __restrict__ point_alpha,
    const float* __restrict__ point_color,
    const float* __restrict__ point_depth,
    const int*   __restrict__ tile_point_indices,
    float* __restrict__ rec, int n)
{
    const int i = blockIdx.x * blockDim.x + threadIdx.x;
    if (i >= n) return;
    const float L2E = 1.4426950408889634f;
    const int gi = tile_point_indices[i];
    const float2 uv = ((const float2*)point_uv)[gi];
    const float ca = point_conic[gi * 3 + 0];
    const float cb = point_conic[gi * 3 + 1];
    const float cc = point_conic[gi * 3 + 2];
    float4* o = (float4*)(rec + (size_t)i * 16);
    o[0] = make_float4(uv.x, uv.y, -0.5f * L2E * ca, -0.5f * L2E * cc);
    o[1] = make_float4(-L2E * cb, __log2f(point_alpha[gi]),
                       point_color[gi * 3 + 0], point_color[gi * 3 + 1]);
    o[2] = make_float4(point_color[gi * 3 + 2], point_depth[gi], 0.0f, 0.0f);
}

// ---------------------------------------------------------------------------
// Kernel 2: rasterize. Per-point data is read via block-uniform addresses
// (blockIdx + loop counter only) -> compiler emits scalar s_load into SGPRs,
// bypassing LDS and the vector-memory path entirely.
// ---------------------------------------------------------------------------
__global__ __launch_bounds__(256, 4) void gsplat_raster_smem_kernel(
    const float* __restrict__ rec,
    const int*   __restrict__ cam_h_p,
    const int*   __restrict__ cam_w_p,
    float* __restrict__ out)
{
    const int t = blockIdx.x;
    const int p = threadIdx.x;

    const int W  = read_dim(cam_w_p);
    const int H  = read_dim(cam_h_p);
    const int TU = W / TILE;
    const int n_pix = H * W;

    const float4* __restrict__ tile_rec =
        (const float4*)(rec + (size_t)t * PPT * 16);

    const int tu = t % TU;
    const int tv = t / TU;
    const int pu = p % TILE;
    const int pv = p / TILE;
    const float pix_u = (float)(tu * TILE + pu) + 0.5f;
    const float pix_v = (float)(tv * TILE + pv) + 0.5f;

    float T = 1.0f;
    float accr = 0.0f, accg = 0.0f, accb = 0.0f;
    float accd = 0.0f, norm = 0.0f;
    int count = 0, last = 0;
    bool sat = false;

    for (int c8 = 0; c8 < PPT / 8; ++c8) {
        #pragma unroll
        for (int k = 0; k < 8; ++k) {
            const int j = c8 * 8 + k;
            // block-uniform loads -> SGPRs (scalar pipe)
            const float4 A = tile_rec[j * 4 + 0];  // u, v, pa, pc
            const float4 B = tile_rec[j * 4 + 1];  // pb, lal, r, g
            const float4 C = tile_rec[j * 4 + 2];  // b, d, -, -

            const float dx = pix_u - A.x;
            const float dy = pix_v - A.y;
            // e = log2(dens*alpha) = pa*dx^2 + pb*dx*dy + pc*dy^2 + lal
            const float e = fmaf(fmaf(A.z, dx, B.x * dy), dx,
                                 fmaf(A.w * dy, dy, B.y));
            const float alpha = EXP2F(e);

            const bool  vis     = alpha >= (1.0f / 255.0f);
            const float alpha_c = fminf(alpha, 0.99f);
            const float one_m   = 1.0f - alpha_c;
            const float Tone    = T * one_m;
            const bool  ntrig   = Tone >= 1e-4f;
            const bool  contrib = vis && ntrig && !sat;
            sat = sat || (vis && !ntrig);

            const float w = contrib ? alpha_c * T : 0.0f;
            accr = fmaf(w, B.z, accr);
            accg = fmaf(w, B.w, accg);
            accb = fmaf(w, C.x, accb);
            accd = fmaf(w, C.y, accd);
            norm += w;
            count += contrib;
            last = contrib ? j + 1 : last;
            T = contrib ? Tone : T;
        }
        if (__all(sat)) break;   // whole wave saturated: remaining w == 0
    }

    const int r = tv * TILE + pv;
    const int c = tu * TILE + pu;
    const int pix = r * W + c;

    out[pix * 3 + 0] = accr;                            // rasterized_image
    out[pix * 3 + 1] = accg;
    out[pix * 3 + 2] = accb;
    out[n_pix * 3 + pix] = accd / fmaxf(norm, 1e-6f);   // rasterized_depth
    out[n_pix * 4 + pix] = 1.0f - T;                    // accumulated_alpha
    out[n_pix * 5 + pix] = (float)(t * PPT + last);     // last_offset
    out[n_pix * 6 + pix] = (float)count;                // valid_count
}

// ---------------------------------------------------------------------------
// Fallback (proven R3 kernel): LDS staging, used only if ws_size is too small.
// ---------------------------------------------------------------------------
__global__ __launch_bounds__(256, 4) void gsplat_raster_lds_kernel(
    const float* __restrict__ point_uv,
    const float* __restrict__ point_conic,
    const float* __restrict__ point_alpha,
    const float* __restrict__ point_color,
    const float* __restrict__ point_depth,
    const int*   __restrict__ tile_point_indices,
    const int*   __restrict__ cam_h_p,
    const int*   __restrict__ cam_w_p,
    float* __restrict__ out)
{
    const int t = blockIdx.x;
    const int p = threadIdx.x;

    const int W  = read_dim(cam_w_p);
    const int H  = read_dim(cam_h_p);
    const int TU = W / TILE;
    const int n_pix = H * W;

    __shared__ float4 sA[PPT];
    __shared__ float4 sB[PPT];

    const float L2E = 1.4426950408889634f;
    if (p < PPT) {
        const int gi = tile_point_indices[t * PPT + p];
        const float2 uv = ((const float2*)point_uv)[gi];
        sA[p] = make_float4(uv.x, uv.y,
                            -0.5f * L2E * point_conic[gi * 3 + 0],
                            -0.5f * L2E * point_conic[gi * 3 + 2]);
    } else if (p < 2 * PPT) {
        const int q  = p - PPT;
        const int gi = tile_point_indices[t * PPT + q];
        const __half2 rg = __floats2half2_rn(point_color[gi * 3 + 0],
                                             point_color[gi * 3 + 1]);
        const __half2 bd = __floats2half2_rn(point_color[gi * 3 + 2],
                                             point_depth[gi]);
        sB[q] = make_float4(-L2E * point_conic[gi * 3 + 1],
                            __log2f(point_alpha[gi]),
                            __builtin_bit_cast(float, rg),
                            __builtin_bit_cast(float, bd));
    }
    __syncthreads();

    const int tu = t % TU;
    const int tv = t / TU;
    const int pu = p % TILE;
    const int pv = p / TILE;
    const float pix_u = (float)(tu * TILE + pu) + 0.5f;
    const float pix_v = (float)(tv * TILE + pv) + 0.5f;

    float T = 1.0f;
    float accr = 0.0f, accg = 0.0f, accb = 0.0f;
    float accd = 0.0f, norm = 0.0f;
    int count = 0, last = 0;
    bool sat = false;

    for (int c8 = 0; c8 < PPT / 8; ++c8) {
        #pragma unroll
        for (int k = 0; k < 8; ++k) {
            const int j = c8 * 8 + k;
            const float4 A = sA[j];
            const float4 B = sB[j];

            const float dx = pix_u - A.x;
            const float dy = pix_v - A.y;
            const float e = fmaf(fmaf(A.z, dx, B.x * dy), dx,
                                 fmaf(A.w * dy, dy, B.y));
            const float alpha = EXP2F(e);

            const bool  vis     = alpha >= (1.0f / 255.0f);
            const float alpha_c = fminf(alpha, 0.99f);
            const float one_m   = 1.0f - alpha_c;
            const float Tone    = T * one_m;
            const bool  ntrig   = Tone >= 1e-4f;
            const bool  contrib = vis && ntrig && !sat;
            sat = sat || (vis && !ntrig);

            const float w = contrib ? alpha_c * T : 0.0f;
            const __half2 rg = __builtin_bit_cast(__half2, B.z);
            const __half2 bd = __builtin_bit_cast(__half2, B.w);
            accr = fmaf(w, __low2float(rg),  accr);
            accg = fmaf(w, __high2float(rg), accg);
            accb = fmaf(w, __low2float(bd),  accb);
            accd = fmaf(w, __high2float(bd), accd);
            norm += w;
            count += contrib;
            last = contrib ? j + 1 : last;
            T = contrib ? Tone : T;
        }
        if (__all(sat)) break;
    }

    const int r = tv * TILE + pv;
    const int c = tu * TILE + pu;
    const int pix = r * W + c;

    out[pix * 3 + 0] = accr;
    out[pix * 3 + 1] = accg;
    out[pix * 3 + 2] = accb;
    out[n_pix * 3 + pix] = accd / fmaxf(norm, 1e-6f);
    out[n_pix * 4 + pix] = 1.0f - T;
    out[n_pix * 5 + pix] = (float)(t * PPT + last);
    out[n_pix * 6 + pix] = (float)count;
}

extern "C" void kernel_launch(void* const* d_in, const int* in_sizes, int n_in,
                              void* d_out, int out_size, void* d_ws, size_t ws_size,
                              hipStream_t stream) {
    const float* point_uv    = (const float*)d_in[0];
    const float* point_conic = (const float*)d_in[1];
    const float* point_alpha = (const float*)d_in[2];
    const float* point_color = (const float*)d_in[3];
    const float* point_depth = (const float*)d_in[4];
    const int*   tpi         = (const int*)d_in[5];
    const int*   cam_h       = (const int*)d_in[6];
    const int*   cam_w       = (const int*)d_in[7];

    const int n_pts = in_sizes[5];       // NT * PPT
    const int NT    = n_pts / PPT;
    const size_t need = (size_t)n_pts * 64;  // 64B record per (tile,point)

    if (ws_size >= need) {
        float* rec = (float*)d_ws;
        gsplat_gather_kernel<<<(n_pts + 255) / 256, 256, 0, stream>>>(
            point_uv, point_conic, point_alpha, point_color, point_depth,
            tpi, rec, n_pts);
        gsplat_raster_smem_kernel<<<NT, 256, 0, stream>>>(
            rec, cam_h, cam_w, (float*)d_out);
    } else {
        gsplat_raster_lds_kernel<<<NT, 256, 0, stream>>>(
            point_uv, point_conic, point_alpha, point_color, point_depth,
            tpi, cam_h, cam_w, (float*)d_out);
    }
}

// Round 5
// 20.039 us; speedup vs baseline: 1.4859x; 1.4859x over previous
//
#include <hip/hip_runtime.h>
#include <hip/hip_fp16.h>

#define TILE 16
#define PPT 64

#if __has_builtin(__builtin_amdgcn_exp2f)
#define EXP2F(x) __builtin_amdgcn_exp2f(x)
#else
#define EXP2F(x) exp2f(x)
#endif

// Robustly read a small positive integer scalar that may have been stored
// as int32 or float32 bits.
__device__ __forceinline__ int read_dim(const int* p) {
    int v = *p;
    if (v >= TILE && v <= 65536 && (v % TILE) == 0) return v;
    float f = __int_as_float(v);
    return (int)f;
}

// One block = one tile = 128 threads (2 waves). Thread p composites TWO
// pixels: (row pv, col pu) and (row pv+8, col pu) — same column, so dx and
// pa*dx are shared between the two pixels. This halves the total number of
// per-iteration LDS broadcast reads vs the 1-pixel/thread version (the
// hypothesized bottleneck: per-CU LDS pipe oversubscription).
__global__ __launch_bounds__(128, 2) void gsplat_raster_kernel(
    const float* __restrict__ point_uv,          // (N,2)
    const float* __restrict__ point_conic,       // (N,3)
    const float* __restrict__ point_alpha,       // (N,)
    const float* __restrict__ point_color,       // (N,3)
    const float* __restrict__ point_depth,       // (N,)
    const int*   __restrict__ tile_point_indices,// (NT,PPT)
    const int*   __restrict__ cam_h_p,
    const int*   __restrict__ cam_w_p,
    float* __restrict__ out)
{
    const int t = blockIdx.x;    // tile id
    const int p = threadIdx.x;   // 0..127

    const int W  = read_dim(cam_w_p);
    const int H  = read_dim(cam_h_p);
    const int TU = W / TILE;
    const int n_pix = H * W;

    // ---- stage 64 points into LDS (2 broadcast b128 reads per iteration) --
    // sA = {u, v, -0.5*log2e*a, -0.5*log2e*c}
    // sB = {-log2e*b, log2(alpha), half2(r,g), half2(b,depth)}
    __shared__ float4 sA[PPT];
    __shared__ float4 sB[PPT];

    const float L2E = 1.4426950408889634f;
    if (p < PPT) {                       // wave 0: A-side
        const int gi = tile_point_indices[t * PPT + p];
        const float2 uv = ((const float2*)point_uv)[gi];
        sA[p] = make_float4(uv.x, uv.y,
                            -0.5f * L2E * point_conic[gi * 3 + 0],
                            -0.5f * L2E * point_conic[gi * 3 + 2]);
    } else {                             // wave 1: B-side
        const int q  = p - PPT;
        const int gi = tile_point_indices[t * PPT + q];
        const __half2 rg = __floats2half2_rn(point_color[gi * 3 + 0],
                                             point_color[gi * 3 + 1]);
        const __half2 bd = __floats2half2_rn(point_color[gi * 3 + 2],
                                             point_depth[gi]);
        sB[q] = make_float4(-L2E * point_conic[gi * 3 + 1],
                            __log2f(point_alpha[gi]),
                            __builtin_bit_cast(float, rg),
                            __builtin_bit_cast(float, bd));
    }
    __syncthreads();

    // ---- pixel coordinates: two pixels per thread, same column ----
    const int tu = t % TU;
    const int tv = t / TU;
    const int pu = p % TILE;        // column within tile (same for both)
    const int pv0 = p / TILE;       // rows 0..7
    const int pv1 = pv0 + 8;        // rows 8..15
    const float pix_u  = (float)(tu * TILE + pu) + 0.5f;
    const float pix_v0 = (float)(tv * TILE + pv0) + 0.5f;
    const float pix_v1 = pix_v0 + 8.0f;

    // ---- branchless front-to-back compositing, 2 pixels ----
    float T0 = 1.0f, T1 = 1.0f;
    float r0 = 0.f, g0 = 0.f, b0 = 0.f, d0 = 0.f, n0 = 0.f;
    float r1 = 0.f, g1 = 0.f, b1 = 0.f, d1 = 0.f, n1 = 0.f;
    int cnt0 = 0, cnt1 = 0, last0 = 0, last1 = 0;
    bool sat0 = false, sat1 = false;

    for (int c8 = 0; c8 < PPT / 8; ++c8) {
        #pragma unroll
        for (int k = 0; k < 8; ++k) {
            const int j = c8 * 8 + k;
            const float4 A = sA[j];   // wave-uniform broadcast
            const float4 B = sB[j];

            // shared between the two pixels (same u)
            const float dx   = pix_u - A.x;
            const float padx = A.z * dx;        // pa*dx
            const __half2 rg = __builtin_bit_cast(__half2, B.z);
            const __half2 bd = __builtin_bit_cast(__half2, B.w);
            const float cr = __low2float(rg),  cg = __high2float(rg);
            const float cb = __low2float(bd),  cd = __high2float(bd);

            // ---- pixel 0 ----
            {
                const float dy = pix_v0 - A.y;
                // e = (pa*dx + pb*dy)*dx + (pc*dy)*dy + lal
                const float e = fmaf(fmaf(B.x, dy, padx), dx,
                                     fmaf(A.w * dy, dy, B.y));
                const float alpha = EXP2F(e);
                const bool  vis     = alpha >= (1.0f / 255.0f);
                const float alpha_c = fminf(alpha, 0.99f);
                const float one_m   = 1.0f - alpha_c;
                const float Tone    = T0 * one_m;
                const bool  ntrig   = Tone >= 1e-4f;
                const bool  contrib = vis && ntrig && !sat0;
                sat0 = sat0 || (vis && !ntrig);
                const float w = contrib ? alpha_c * T0 : 0.0f;
                r0 = fmaf(w, cr, r0);  g0 = fmaf(w, cg, g0);
                b0 = fmaf(w, cb, b0);  d0 = fmaf(w, cd, d0);
                n0 += w;
                cnt0 += contrib;
                last0 = contrib ? j + 1 : last0;
                T0 = contrib ? Tone : T0;
            }
            // ---- pixel 1 ----
            {
                const float dy = pix_v1 - A.y;
                const float e = fmaf(fmaf(B.x, dy, padx), dx,
                                     fmaf(A.w * dy, dy, B.y));
                const float alpha = EXP2F(e);
                const bool  vis     = alpha >= (1.0f / 255.0f);
                const float alpha_c = fminf(alpha, 0.99f);
                const float one_m   = 1.0f - alpha_c;
                const float Tone    = T1 * one_m;
                const bool  ntrig   = Tone >= 1e-4f;
                const bool  contrib = vis && ntrig && !sat1;
                sat1 = sat1 || (vis && !ntrig);
                const float w = contrib ? alpha_c * T1 : 0.0f;
                r1 = fmaf(w, cr, r1);  g1 = fmaf(w, cg, g1);
                b1 = fmaf(w, cb, b1);  d1 = fmaf(w, cd, d1);
                n1 += w;
                cnt1 += contrib;
                last1 = contrib ? j + 1 : last1;
                T1 = contrib ? Tone : T1;
            }
        }
        if (__all(sat0 && sat1)) break;   // wave fully saturated
    }

    // ---- write outputs (image layout) ----
    const int c  = tu * TILE + pu;
    const int row0 = tv * TILE + pv0;
    const int pix0 = row0 * W + c;
    const int pix1 = pix0 + 8 * W;

    out[pix0 * 3 + 0] = r0;
    out[pix0 * 3 + 1] = g0;
    out[pix0 * 3 + 2] = b0;
    out[n_pix * 3 + pix0] = d0 / fmaxf(n0, 1e-6f);
    out[n_pix * 4 + pix0] = 1.0f - T0;
    out[n_pix * 5 + pix0] = (float)(t * PPT + last0);
    out[n_pix * 6 + pix0] = (float)cnt0;

    out[pix1 * 3 + 0] = r1;
    out[pix1 * 3 + 1] = g1;
    out[pix1 * 3 + 2] = b1;
    out[n_pix * 3 + pix1] = d1 / fmaxf(n1, 1e-6f);
    out[n_pix * 4 + pix1] = 1.0f - T1;
    out[n_pix * 5 + pix1] = (float)(t * PPT + last1);
    out[n_pix * 6 + pix1] = (float)cnt1;
}

extern "C" void kernel_launch(void* const* d_in, const int* in_sizes, int n_in,
                              void* d_out, int out_size, void* d_ws, size_t ws_size,
                              hipStream_t stream) {
    const float* point_uv    = (const float*)d_in[0];
    const float* point_conic = (const float*)d_in[1];
    const float* point_alpha = (const float*)d_in[2];
    const float* point_color = (const float*)d_in[3];
    const float* point_depth = (const float*)d_in[4];
    const int*   tpi         = (const int*)d_in[5];
    const int*   cam_h       = (const int*)d_in[6];
    const int*   cam_w       = (const int*)d_in[7];

    const int NT = in_sizes[5] / PPT;  // number of tiles

    gsplat_raster_kernel<<<NT, 128, 0, stream>>>(
        point_uv, point_conic, point_alpha, point_color, point_depth,
        tpi, cam_h, cam_w, (float*)d_out);
}